// Round 4
// baseline (929.677 us; speedup 1.0000x reference)
//
#include <hip/hip_runtime.h>

#define N_NODES 100000
#define N_EDGES 1600000
#define D 128
#define DH 256
#define N_GRAPHS 512
#define EPS 1e-5f
#define NBUCK 3125   // N_NODES / 32
#define BCAP 1536    // LDS sort capacity per bucket (mean 512, ~45 sigma margin)

typedef _Float16 h8 __attribute__((ext_vector_type(8)));
typedef float f4 __attribute__((ext_vector_type(4)));

// ---------------- preprocessing ----------------

// per-node degree count + per-bucket histogram (bucket = dst>>5)
__global__ __launch_bounds__(1024) void k_count_hist(const int* __restrict__ dst,
                                                     int* __restrict__ cnt,
                                                     int* __restrict__ bcnt) {
    __shared__ int lh[NBUCK];
    for (int i = threadIdx.x; i < NBUCK; i += 1024) lh[i] = 0;
    __syncthreads();
    int base = blockIdx.x * 16384;
    int lim = min(16384, N_EDGES - base);
    for (int i = threadIdx.x; i < lim; i += 1024) {
        int d = dst[base + i];
        atomicAdd(&cnt[d], 1);
        atomicAdd(&lh[d >> 5], 1);
    }
    __syncthreads();
    for (int i = threadIdx.x; i < NBUCK; i += 1024)
        if (lh[i]) atomicAdd(&bcnt[i], lh[i]);
}

__global__ void k_dinv(const int* __restrict__ cnt, float* __restrict__ dinv) {
    int i = blockIdx.x * 256 + threadIdx.x;
    if (i < N_NODES) dinv[i] = rsqrtf((float)(cnt[i] + 1));
}

__global__ void k_scan1(const int* __restrict__ in, int* __restrict__ out,
                        int* __restrict__ bsums, int n) {
    __shared__ int tmp[256];
    int gid = blockIdx.x * 256 + threadIdx.x;
    int v = (gid < n) ? in[gid] : 0;
    tmp[threadIdx.x] = v;
    __syncthreads();
    for (int off = 1; off < 256; off <<= 1) {
        int t = (threadIdx.x >= off) ? tmp[threadIdx.x - off] : 0;
        __syncthreads();
        tmp[threadIdx.x] += t;
        __syncthreads();
    }
    if (gid < n) out[gid] = tmp[threadIdx.x] - v;
    if (threadIdx.x == 255) bsums[blockIdx.x] = tmp[255];
}

__global__ void k_scan2(int* __restrict__ bsums, int nb) {
    __shared__ int tmp[512];
    int v = (threadIdx.x < nb) ? bsums[threadIdx.x] : 0;
    tmp[threadIdx.x] = v;
    __syncthreads();
    for (int off = 1; off < 512; off <<= 1) {
        int t = (threadIdx.x >= off) ? tmp[threadIdx.x - off] : 0;
        __syncthreads();
        tmp[threadIdx.x] += t;
        __syncthreads();
    }
    if (threadIdx.x < nb) bsums[threadIdx.x] = tmp[threadIdx.x] - v;
}

__global__ void k_scan3(int* __restrict__ out, const int* __restrict__ bsums, int n) {
    int gid = blockIdx.x * 256 + threadIdx.x;
    if (gid < n) out[gid] += bsums[blockIdx.x];
    if (gid == 0) out[n] = N_EDGES;
}

// exclusive scan of bcnt[NBUCK] -> boffs[NBUCK+1], single block
__global__ __launch_bounds__(1024) void k_bscan(const int* __restrict__ bcnt,
                                                int* __restrict__ boffs) {
    __shared__ int tmp[1024];
    __shared__ int carry;
    if (threadIdx.x == 0) carry = 0;
    __syncthreads();
    for (int chunk = 0; chunk < (NBUCK + 1023) / 1024; ++chunk) {
        int idx = chunk * 1024 + threadIdx.x;
        int v = (idx < NBUCK) ? bcnt[idx] : 0;
        tmp[threadIdx.x] = v;
        __syncthreads();
        for (int off = 1; off < 1024; off <<= 1) {
            int t = (threadIdx.x >= off) ? tmp[threadIdx.x - off] : 0;
            __syncthreads();
            tmp[threadIdx.x] += t;
            __syncthreads();
        }
        int cbase = carry;
        if (idx < NBUCK) boffs[idx] = cbase + tmp[threadIdx.x] - v;
        __syncthreads();
        if (threadIdx.x == 0) carry = cbase + tmp[1023];
        __syncthreads();
    }
    if (threadIdx.x == 0) boffs[NBUCK] = N_EDGES;
}

// scatter packed (dlow<<17 | src) into bucket-contiguous regions
__global__ void k_bfill(const int* __restrict__ src, const int* __restrict__ dst,
                        const int* __restrict__ boffs, int* __restrict__ bcur,
                        unsigned* __restrict__ packed) {
    int e = blockIdx.x * 256 + threadIdx.x;
    if (e < N_EDGES) {
        int d = dst[e];
        int b = d >> 5;
        int pos = boffs[b] + atomicAdd(&bcur[b], 1);
        packed[pos] = ((unsigned)(d & 31) << 17) | (unsigned)src[e];
    }
}

// per-bucket LDS counting sort by dst -> coalesced csr segment write
__global__ __launch_bounds__(256) void k_bsort(const unsigned* __restrict__ packed,
                                               const int* __restrict__ boffs,
                                               const int* __restrict__ offs,
                                               int* __restrict__ csr) {
    int b = blockIdx.x;
    int beg = boffs[b];
    int cntb = boffs[b + 1] - beg;
    __shared__ int hist[32], hist2[32], scan[32];
    __shared__ int sorted[BCAP];
    if (threadIdx.x < 32) {
        hist[threadIdx.x] = 0;
        hist2[threadIdx.x] = 0;
    }
    __syncthreads();
    for (int i = threadIdx.x; i < cntb; i += 256)
        atomicAdd(&hist[packed[beg + i] >> 17], 1);
    __syncthreads();
    if (threadIdx.x == 0) {
        int s = 0;
        for (int j = 0; j < 32; ++j) {
            scan[j] = s;
            s += hist[j];
        }
    }
    __syncthreads();
    int gbase = offs[b << 5];
    if (cntb <= BCAP) {
        for (int i = threadIdx.x; i < cntb; i += 256) {
            unsigned p = packed[beg + i];
            int dl = p >> 17;
            int r = atomicAdd(&hist2[dl], 1);
            sorted[scan[dl] + r] = (int)(p & 0x1FFFF);
        }
        __syncthreads();
        for (int i = threadIdx.x; i < cntb; i += 256) csr[gbase + i] = sorted[i];
    } else {
        for (int i = threadIdx.x; i < cntb; i += 256) {
            unsigned p = packed[beg + i];
            int dl = p >> 17;
            int r = atomicAdd(&hist2[dl], 1);
            csr[gbase + scan[dl] + r] = (int)(p & 0x1FFFF);
        }
    }
}

// cast fp32 x -> fp16 (half8 per thread)
__global__ void k_cast(const float4* __restrict__ x4, h8* __restrict__ xh, int n8) {
    int i = blockIdx.x * 256 + threadIdx.x;
    if (i >= n8) return;
    float4 a = x4[2 * i], b = x4[2 * i + 1];
    h8 o;
    o[0] = (_Float16)a.x; o[1] = (_Float16)a.y; o[2] = (_Float16)a.z; o[3] = (_Float16)a.w;
    o[4] = (_Float16)b.x; o[5] = (_Float16)b.y; o[6] = (_Float16)b.z; o[7] = (_Float16)b.w;
    xh[i] = o;
}

// BN fold merged: blocks 0..63: WT[n][k] = a[k]*W[k][n] (fp16); block 64: r[j]
__global__ void k_fold(const float* __restrict__ W, const float* __restrict__ a,
                       const float* __restrict__ c, int use_bn,
                       _Float16* __restrict__ WT, float* __restrict__ r) {
    if (blockIdx.x < 64) {
        int idx = blockIdx.x * 256 + threadIdx.x;
        int n = idx >> 7, k = idx & 127;
        float s = use_bn ? a[k] : 1.0f;
        WT[idx] = (_Float16)(s * W[k * D + n]);
    } else if (threadIdx.x < 128) {
        int j = threadIdx.x;
        float s = 0.f;
        if (use_bn)
            for (int k = 0; k < D; ++k) s = fmaf(c[k], W[k * D + j], s);
        r[j] = s;
    }
}

// ---------------- MFMA GEMM: Y[nrows,128] = X @ W + r, fp16 in/out ----------
__global__ __launch_bounds__(256) void k_gemm(const _Float16* __restrict__ X,
                                              const _Float16* __restrict__ WT,
                                              const float* __restrict__ radd,
                                              _Float16* __restrict__ Y, int nrows) {
    __shared__ _Float16 Wl[128][136];
    __shared__ _Float16 Yl[64][136];
    int t = threadIdx.x;
    {
        const h8* src = (const h8*)WT;
        for (int i = t; i < 128 * 16; i += 256) {
            int r = i >> 4, c = i & 15;
            *(h8*)&Wl[r][c * 8] = src[i];
        }
    }
    int wave = t >> 6;
    int lane = t & 63;
    int l15 = lane & 15;
    int quad = lane >> 4;
    int rowblk = blockIdx.x * 64;
    int row0 = rowblk + wave * 16;

    h8 zero8;
#pragma unroll
    for (int j = 0; j < 8; ++j) zero8[j] = (_Float16)0;

    h8 a[4];
    bool inb = (row0 + l15) < nrows;
    const _Float16* xrow = X + (size_t)(row0 + l15) * D + quad * 8;
#pragma unroll
    for (int kt = 0; kt < 4; ++kt) a[kt] = inb ? *(const h8*)(xrow + kt * 32) : zero8;

    __syncthreads();

    f4 acc[8];
#pragma unroll
    for (int n = 0; n < 8; ++n) {
        acc[n][0] = 0.f; acc[n][1] = 0.f; acc[n][2] = 0.f; acc[n][3] = 0.f;
#pragma unroll
        for (int kt = 0; kt < 4; ++kt) {
            h8 b = *(const h8*)&Wl[n * 16 + l15][kt * 32 + quad * 8];
            acc[n] = __builtin_amdgcn_mfma_f32_16x16x32_f16(a[kt], b, acc[n], 0, 0, 0);
        }
    }
#pragma unroll
    for (int n = 0; n < 8; ++n) {
        float r = radd[n * 16 + l15];
#pragma unroll
        for (int i = 0; i < 4; ++i)
            Yl[wave * 16 + quad * 4 + i][n * 16 + l15] = (_Float16)(acc[n][i] + r);
    }
    __syncthreads();
    for (int i = t; i < 64 * 16; i += 256) {
        int r = i >> 4, c = i & 15;
        if (rowblk + r < nrows)
            *(h8*)&Y[(size_t)(rowblk + r) * D + c * 8] = *(h8*)&Yl[r][c * 8];
    }
}

// ---------------- aggregate + relu + fused BN partial stats ----------------
__global__ __launch_bounds__(256) void k_aggregate(const h8* __restrict__ Y8,
                                                   const int* __restrict__ offs,
                                                   const int* __restrict__ csr,
                                                   const float* __restrict__ dinv,
                                                   const float* __restrict__ bias,
                                                   h8* __restrict__ A8,
                                                   float* __restrict__ part) {
    int grp = threadIdx.x >> 4;
    int lane = threadIdx.x & 15;
    int node = blockIdx.x * 16 + grp;
    int beg = offs[node], end = offs[node + 1];
    float dn = dinv[node];
    float acc[8];
    h8 y = Y8[(size_t)node * 16 + lane];
#pragma unroll
    for (int i = 0; i < 8; ++i) acc[i] = dn * (float)y[i];
    for (int e = beg; e < end; ++e) {
        int s = csr[e];
        float ds = dinv[s];
        h8 v = Y8[(size_t)s * 16 + lane];
#pragma unroll
        for (int i = 0; i < 8; ++i) acc[i] = fmaf(ds, (float)v[i], acc[i]);
    }
    __shared__ float red[16][128];
    h8 o;
#pragma unroll
    for (int i = 0; i < 8; ++i) {
        float v = fmaxf(fmaf(acc[i], dn, bias[lane * 8 + i]), 0.f);
        o[i] = (_Float16)v;
        red[grp][lane * 8 + i] = v;
    }
    A8[(size_t)node * 16 + lane] = o;
    __syncthreads();
    if (threadIdx.x < 128) {
        int c = threadIdx.x;
        float s = 0.f, s2 = 0.f;
#pragma unroll
        for (int g = 0; g < 16; ++g) {
            float v = red[g][c];
            s += v;
            s2 = fmaf(v, v, s2);
        }
        float* p = part + (size_t)(blockIdx.x & 31) * 256;
        atomicAdd(&p[c], s);
        atomicAdd(&p[128 + c], s2);
    }
}

__global__ void k_bn_coeffs(const float* __restrict__ part, int stripes, int stride,
                            int coff, const float* __restrict__ g,
                            const float* __restrict__ beta, float* __restrict__ a,
                            float* __restrict__ c, float inv_n) {
    int i = threadIdx.x;
    float s = 0.f, s2 = 0.f;
    for (int st = 0; st < stripes; ++st) {
        s += part[st * stride + i];
        s2 += part[st * stride + coff + i];
    }
    float m = s * inv_n;
    float v = s2 * inv_n - m * m;
    float ai = g[i] * rsqrtf(v + EPS);
    a[i] = ai;
    c[i] = beta[i] - m * ai;
}

// ---------------- pooling + MLP head ----------------

__global__ void k_starts(const int* __restrict__ batch, int* __restrict__ starts) {
    int n = blockIdx.x * 256 + threadIdx.x;
    if (n >= N_NODES) return;
    int b = batch[n];
    int prev = (n == 0) ? -1 : batch[n - 1];
    for (int g = prev + 1; g <= b; ++g) starts[g] = n;
    if (n == N_NODES - 1)
        for (int g = b + 1; g <= N_GRAPHS; ++g) starts[g] = N_NODES;
}

__global__ void k_pool(const h8* __restrict__ x8, const int* __restrict__ starts,
                       const float* __restrict__ a, const float* __restrict__ c,
                       float* __restrict__ pooled) {
    int grp = threadIdx.x >> 4;
    int lane = threadIdx.x & 15;
    int g = blockIdx.x * 8 + grp;
    int beg = starts[g], end = starts[g + 1];
    float s[8] = {};
    for (int n = beg; n < end; ++n) {
        h8 v = x8[(size_t)n * 16 + lane];
#pragma unroll
        for (int i = 0; i < 8; ++i) s[i] += (float)v[i];
    }
    float cnt = (float)(end - beg);
#pragma unroll
    for (int i = 0; i < 8; ++i) {
        int ch = lane * 8 + i;
        pooled[g * D + ch] = fmaf(a[ch], s[i], cnt * c[ch]);
    }
}

__global__ void k_dense_relu(const float* __restrict__ in, const float* __restrict__ W,
                             const float* __restrict__ b, float* __restrict__ out,
                             int K, int N) {
    int row = blockIdx.x;
    int j = threadIdx.x;
    if (j >= N) return;
    float acc = b[j];
    for (int k = 0; k < K; ++k) acc = fmaf(in[row * K + k], W[k * N + j], acc);
    out[row * N + j] = fmaxf(acc, 0.0f);
}

__global__ void k_head_stats(const float* __restrict__ x, float* __restrict__ sums,
                             float* __restrict__ sumsq, int rows) {
    int c = threadIdx.x;
    float s = 0.f, s2 = 0.f;
    int r0 = blockIdx.x * 8;
    int r1 = min(r0 + 8, rows);
    for (int r = r0; r < r1; ++r) {
        float v = x[r * DH + c];
        s += v;
        s2 = fmaf(v, v, s2);
    }
    atomicAdd(&sums[c], s);
    atomicAdd(&sumsq[c], s2);
}

__global__ void k_head_apply(float* __restrict__ x, const float* __restrict__ a,
                             const float* __restrict__ c) {
    int i = blockIdx.x * 256 + threadIdx.x;
    float4 v = ((float4*)x)[i];
    int col = (i << 2) & 255;
    v.x = fmaf(v.x, a[col], c[col]);
    v.y = fmaf(v.y, a[col + 1], c[col + 1]);
    v.z = fmaf(v.z, a[col + 2], c[col + 2]);
    v.w = fmaf(v.w, a[col + 3], c[col + 3]);
    ((float4*)x)[i] = v;
}

__global__ void k_final(const float* __restrict__ h, const float* __restrict__ Wout,
                        const float* __restrict__ bout, float* __restrict__ out) {
    int g = blockIdx.x * 256 + threadIdx.x;
    if (g >= N_GRAPHS) return;
    float acc = bout[0];
    for (int k = 0; k < DH; ++k) acc = fmaf(h[g * DH + k], Wout[k], acc);
    out[g] = acc;
}

// ---------------- launch ----------------

extern "C" void kernel_launch(void* const* d_in, const int* in_sizes, int n_in,
                              void* d_out, int out_size, void* d_ws, size_t ws_size,
                              hipStream_t stream) {
    const float* x = (const float*)d_in[0];
    const int* ei = (const int*)d_in[1];
    const int* batch = (const int*)d_in[2];
    const float* Wc = (const float*)d_in[3];
    const float* bc = (const float*)d_in[4];
    const float* gc = (const float*)d_in[5];
    const float* bec = (const float*)d_in[6];
    const float* Wh0 = (const float*)d_in[7];
    const float* bh0 = (const float*)d_in[8];
    const float* gh0 = (const float*)d_in[9];
    const float* beh0 = (const float*)d_in[10];
    const float* Wh1 = (const float*)d_in[11];
    const float* bh1 = (const float*)d_in[12];
    const float* gh1 = (const float*)d_in[13];
    const float* beh1 = (const float*)d_in[14];
    const float* Wout = (const float*)d_in[15];
    const float* bout = (const float*)d_in[16];
    float* out = (float*)d_out;

    const int* src = ei;
    const int* dst = ei + N_EDGES;

    char* base = (char*)d_ws;
    size_t woff = 0;
    auto alloc = [&](size_t bytes) -> char* {
        char* p = base + woff;
        woff = (woff + bytes + 255) & ~(size_t)255;
        return p;
    };
    _Float16* xh = (_Float16*)alloc(sizeof(_Float16) * (size_t)N_NODES * D);
    _Float16* bufY = (_Float16*)alloc(sizeof(_Float16) * (size_t)N_NODES * D);
    _Float16* bufA = (_Float16*)alloc(sizeof(_Float16) * (size_t)N_NODES * D);
    float* dinv = (float*)alloc(sizeof(float) * N_NODES);
    int* csr = (int*)alloc(sizeof(int) * N_EDGES);
    unsigned* packed = (unsigned*)alloc(sizeof(unsigned) * N_EDGES);
    // zeroed region: cnt + bcnt + bcur contiguous
    int* cnt = (int*)alloc(sizeof(int) * (N_NODES + 2 * NBUCK));
    int* bcnt = cnt + N_NODES;
    int* bcur = bcnt + NBUCK;
    int* offs = (int*)alloc(sizeof(int) * (N_NODES + 1));
    int* boffs = (int*)alloc(sizeof(int) * (NBUCK + 1));
    int* bsums = (int*)alloc(sizeof(int) * 512);
    float* part = (float*)alloc(sizeof(float) * 32 * 256);
    float* stats = (float*)alloc(sizeof(float) * 512);
    float* sums = stats;
    float* sumsq = stats + 256;
    float* avec = (float*)alloc(sizeof(float) * 256);
    float* cvec = (float*)alloc(sizeof(float) * 256);
    _Float16* WT = (_Float16*)alloc(sizeof(_Float16) * D * D);
    float* rvec = (float*)alloc(sizeof(float) * 128);
    int* starts = (int*)alloc(sizeof(int) * (N_GRAPHS + 1));
    float* pooled = (float*)alloc(sizeof(float) * N_GRAPHS * D);
    float* h0 = (float*)alloc(sizeof(float) * N_GRAPHS * DH);
    float* h1 = (float*)alloc(sizeof(float) * N_GRAPHS * DH);

    hipMemsetAsync(cnt, 0, sizeof(int) * (N_NODES + 2 * NBUCK), stream);

    int ebl = (N_EDGES + 255) / 256;
    int nbl = (N_NODES + 255) / 256;
    k_count_hist<<<(N_EDGES + 16383) / 16384, 1024, 0, stream>>>(dst, cnt, bcnt);
    k_dinv<<<nbl, 256, 0, stream>>>(cnt, dinv);
    k_scan1<<<nbl, 256, 0, stream>>>(cnt, offs, bsums, N_NODES);
    k_scan2<<<1, 512, 0, stream>>>(bsums, nbl);
    k_scan3<<<nbl, 256, 0, stream>>>(offs, bsums, N_NODES);
    k_bscan<<<1, 1024, 0, stream>>>(bcnt, boffs);
    k_bfill<<<ebl, 256, 0, stream>>>(src, dst, boffs, bcur, packed);
    k_bsort<<<NBUCK, 256, 0, stream>>>(packed, boffs, offs, csr);
    k_cast<<<(N_NODES * D / 8 + 255) / 256, 256, 0, stream>>>((const float4*)x,
                                                              (h8*)xh, N_NODES * D / 8);

    const _Float16* cur_in = xh;
    int gemm_grid = (N_NODES + 63) / 64;
    for (int layer = 0; layer < 3; ++layer) {
        k_fold<<<65, 256, 0, stream>>>(Wc + layer * D * D, avec, cvec, layer > 0, WT, rvec);
        k_gemm<<<gemm_grid, 256, 0, stream>>>(cur_in, WT, rvec, bufY, N_NODES);
        hipMemsetAsync(part, 0, sizeof(float) * 32 * 256, stream);
        k_aggregate<<<N_NODES / 16, 256, 0, stream>>>(
            (const h8*)bufY, offs, csr, dinv, bc + layer * D, (h8*)bufA, part);
        k_bn_coeffs<<<1, 128, 0, stream>>>(part, 32, 256, 128, gc + layer * D,
                                           bec + layer * D, avec, cvec, 1.0f / N_NODES);
        cur_in = bufA;
    }

    k_starts<<<nbl, 256, 0, stream>>>(batch, starts);
    k_pool<<<N_GRAPHS / 8, 128, 0, stream>>>((const h8*)bufA, starts, avec, cvec, pooled);

    k_dense_relu<<<N_GRAPHS, 256, 0, stream>>>(pooled, Wh0, bh0, h0, D, DH);
    hipMemsetAsync(stats, 0, sizeof(float) * 512, stream);
    k_head_stats<<<64, 256, 0, stream>>>(h0, sums, sumsq, N_GRAPHS);
    k_bn_coeffs<<<1, 256, 0, stream>>>(stats, 1, 512, 256, gh0, beh0, avec, cvec,
                                       1.0f / N_GRAPHS);
    k_head_apply<<<N_GRAPHS * DH / 4 / 256, 256, 0, stream>>>(h0, avec, cvec);

    k_dense_relu<<<N_GRAPHS, 256, 0, stream>>>(h0, Wh1, bh1, h1, DH, DH);
    hipMemsetAsync(stats, 0, sizeof(float) * 512, stream);
    k_head_stats<<<64, 256, 0, stream>>>(h1, sums, sumsq, N_GRAPHS);
    k_bn_coeffs<<<1, 256, 0, stream>>>(stats, 1, 512, 256, gh1, beh1, avec, cvec,
                                       1.0f / N_GRAPHS);
    k_head_apply<<<N_GRAPHS * DH / 4 / 256, 256, 0, stream>>>(h1, avec, cvec);

    k_final<<<2, 256, 0, stream>>>(h1, Wout, bout, out);
}

// Round 5
// 836.372 us; speedup vs baseline: 1.1116x; 1.1116x over previous
//
#include <hip/hip_runtime.h>

#define N_NODES 100000
#define N_EDGES 1600000
#define D 128
#define DH 256
#define N_GRAPHS 512
#define EPS 1e-5f
#define NPART 8
#define PSIZE 12500      // N_NODES / NPART
#define FCHUNK 4096      // edges per fill chunk

typedef _Float16 h8 __attribute__((ext_vector_type(8)));
typedef float f4 __attribute__((ext_vector_type(4)));

// ---------------- preprocessing ----------------

// XCD-partitioned degree count: block handles partition (blockIdx&7) only
__global__ void k_count_part(const int* __restrict__ dst, int* __restrict__ cnt) {
    int part = blockIdx.x & 7;
    int base = (blockIdx.x >> 3) * FCHUNK;
    int lo = part * PSIZE, hi = lo + PSIZE;
    int lim = min(FCHUNK, N_EDGES - base);
    for (int i = threadIdx.x; i < lim; i += 256) {
        int d = dst[base + i];
        if (d >= lo && d < hi) atomicAdd(&cnt[d], 1);
    }
}

// scan within 256-blocks; also emits dinv = rsqrt(cnt+1)
__global__ void k_scan1(const int* __restrict__ in, int* __restrict__ out,
                        int* __restrict__ bsums, float* __restrict__ dinv, int n) {
    __shared__ int tmp[256];
    int gid = blockIdx.x * 256 + threadIdx.x;
    int v = (gid < n) ? in[gid] : 0;
    if (gid < n) dinv[gid] = rsqrtf((float)(v + 1));
    tmp[threadIdx.x] = v;
    __syncthreads();
    for (int off = 1; off < 256; off <<= 1) {
        int t = (threadIdx.x >= off) ? tmp[threadIdx.x - off] : 0;
        __syncthreads();
        tmp[threadIdx.x] += t;
        __syncthreads();
    }
    if (gid < n) out[gid] = tmp[threadIdx.x] - v;
    if (threadIdx.x == 255) bsums[blockIdx.x] = tmp[255];
}

__global__ void k_scan2(int* __restrict__ bsums, int nb) {
    __shared__ int tmp[512];
    int v = (threadIdx.x < nb) ? bsums[threadIdx.x] : 0;
    tmp[threadIdx.x] = v;
    __syncthreads();
    for (int off = 1; off < 512; off <<= 1) {
        int t = (threadIdx.x >= off) ? tmp[threadIdx.x - off] : 0;
        __syncthreads();
        tmp[threadIdx.x] += t;
        __syncthreads();
    }
    if (threadIdx.x < nb) bsums[threadIdx.x] = tmp[threadIdx.x] - v;
}

__global__ void k_scan3(int* __restrict__ out, const int* __restrict__ bsums, int n) {
    int gid = blockIdx.x * 256 + threadIdx.x;
    if (gid < n) out[gid] += bsums[blockIdx.x];
    if (gid == 0) out[n] = N_EDGES;
}

// XCD-partitioned CSR scatter: block (chunk, part) writes only its node range,
// so csr lines + cursor atomics stay in one XCD's L2 (blockIdx%8 ~ XCD).
__global__ void k_fill_part(const int* __restrict__ src, const int* __restrict__ dst,
                            const int* __restrict__ offs, int* __restrict__ cursor,
                            int* __restrict__ csr) {
    int part = blockIdx.x & 7;
    int base = (blockIdx.x >> 3) * FCHUNK;
    int lo = part * PSIZE, hi = lo + PSIZE;
    int lim = min(FCHUNK, N_EDGES - base);
    for (int i = threadIdx.x; i < lim; i += 256) {
        int d = dst[base + i];
        if (d >= lo && d < hi) {
            int pos = offs[d] + atomicAdd(&cursor[d], 1);
            csr[pos] = src[base + i];
        }
    }
}

// cast fp32 x -> fp16 (half8 per thread)
__global__ void k_cast(const float4* __restrict__ x4, h8* __restrict__ xh, int n8) {
    int i = blockIdx.x * 256 + threadIdx.x;
    if (i >= n8) return;
    float4 a = x4[2 * i], b = x4[2 * i + 1];
    h8 o;
    o[0] = (_Float16)a.x; o[1] = (_Float16)a.y; o[2] = (_Float16)a.z; o[3] = (_Float16)a.w;
    o[4] = (_Float16)b.x; o[5] = (_Float16)b.y; o[6] = (_Float16)b.z; o[7] = (_Float16)b.w;
    xh[i] = o;
}

// BN fold merged: blocks 0..63: WT[n][k] = a[k]*W[k][n] (fp16); block 64: r[j]
__global__ void k_fold(const float* __restrict__ W, const float* __restrict__ a,
                       const float* __restrict__ c, int use_bn,
                       _Float16* __restrict__ WT, float* __restrict__ r) {
    if (blockIdx.x < 64) {
        int idx = blockIdx.x * 256 + threadIdx.x;
        int n = idx >> 7, k = idx & 127;
        float s = use_bn ? a[k] : 1.0f;
        WT[idx] = (_Float16)(s * W[k * D + n]);
    } else if (threadIdx.x < 128) {
        int j = threadIdx.x;
        float s = 0.f;
        if (use_bn)
            for (int k = 0; k < D; ++k) s = fmaf(c[k], W[k * D + j], s);
        r[j] = s;
    }
}

// ---------------- MFMA GEMM: Y[nrows,128] = X @ W + r, fp16 in/out ----------
__global__ __launch_bounds__(256) void k_gemm(const _Float16* __restrict__ X,
                                              const _Float16* __restrict__ WT,
                                              const float* __restrict__ radd,
                                              _Float16* __restrict__ Y, int nrows) {
    __shared__ _Float16 Wl[128][136];
    __shared__ _Float16 Yl[64][136];
    int t = threadIdx.x;
    {
        const h8* src = (const h8*)WT;
        for (int i = t; i < 128 * 16; i += 256) {
            int r = i >> 4, c = i & 15;
            *(h8*)&Wl[r][c * 8] = src[i];
        }
    }
    int wave = t >> 6;
    int lane = t & 63;
    int l15 = lane & 15;
    int quad = lane >> 4;
    int rowblk = blockIdx.x * 64;
    int row0 = rowblk + wave * 16;

    h8 zero8;
#pragma unroll
    for (int j = 0; j < 8; ++j) zero8[j] = (_Float16)0;

    h8 a[4];
    bool inb = (row0 + l15) < nrows;
    const _Float16* xrow = X + (size_t)(row0 + l15) * D + quad * 8;
#pragma unroll
    for (int kt = 0; kt < 4; ++kt) a[kt] = inb ? *(const h8*)(xrow + kt * 32) : zero8;

    __syncthreads();

    f4 acc[8];
#pragma unroll
    for (int n = 0; n < 8; ++n) {
        acc[n][0] = 0.f; acc[n][1] = 0.f; acc[n][2] = 0.f; acc[n][3] = 0.f;
#pragma unroll
        for (int kt = 0; kt < 4; ++kt) {
            h8 b = *(const h8*)&Wl[n * 16 + l15][kt * 32 + quad * 8];
            acc[n] = __builtin_amdgcn_mfma_f32_16x16x32_f16(a[kt], b, acc[n], 0, 0, 0);
        }
    }
#pragma unroll
    for (int n = 0; n < 8; ++n) {
        float r = radd[n * 16 + l15];
#pragma unroll
        for (int i = 0; i < 4; ++i)
            Yl[wave * 16 + quad * 4 + i][n * 16 + l15] = (_Float16)(acc[n][i] + r);
    }
    __syncthreads();
    for (int i = t; i < 64 * 16; i += 256) {
        int r = i >> 4, c = i & 15;
        if (rowblk + r < nrows)
            *(h8*)&Y[(size_t)(rowblk + r) * D + c * 8] = *(h8*)&Yl[r][c * 8];
    }
}

// ---------------- aggregate + relu + fused BN partial stats ----------------
__global__ __launch_bounds__(256) void k_aggregate(const h8* __restrict__ Y8,
                                                   const int* __restrict__ offs,
                                                   const int* __restrict__ csr,
                                                   const float* __restrict__ dinv,
                                                   const float* __restrict__ bias,
                                                   h8* __restrict__ A8,
                                                   float* __restrict__ part) {
    int grp = threadIdx.x >> 4;
    int lane = threadIdx.x & 15;
    int node = blockIdx.x * 16 + grp;
    int beg = offs[node], end = offs[node + 1];
    float dn = dinv[node];
    float acc[8];
    h8 y = Y8[(size_t)node * 16 + lane];
#pragma unroll
    for (int i = 0; i < 8; ++i) acc[i] = dn * (float)y[i];
    for (int e = beg; e < end; ++e) {
        int s = csr[e];
        float ds = dinv[s];
        h8 v = Y8[(size_t)s * 16 + lane];
#pragma unroll
        for (int i = 0; i < 8; ++i) acc[i] = fmaf(ds, (float)v[i], acc[i]);
    }
    __shared__ float red[16][128];
    h8 o;
#pragma unroll
    for (int i = 0; i < 8; ++i) {
        float v = fmaxf(fmaf(acc[i], dn, bias[lane * 8 + i]), 0.f);
        o[i] = (_Float16)v;
        red[grp][lane * 8 + i] = v;
    }
    A8[(size_t)node * 16 + lane] = o;
    __syncthreads();
    if (threadIdx.x < 128) {
        int c = threadIdx.x;
        float s = 0.f, s2 = 0.f;
#pragma unroll
        for (int g = 0; g < 16; ++g) {
            float v = red[g][c];
            s += v;
            s2 = fmaf(v, v, s2);
        }
        float* p = part + (size_t)(blockIdx.x & 31) * 256;
        atomicAdd(&p[c], s);
        atomicAdd(&p[128 + c], s2);
    }
}

// BN coeffs from striped partials; re-zeroes partials for the next user
__global__ void k_bn_coeffs(float* __restrict__ part, int stripes, int stride,
                            int coff, const float* __restrict__ g,
                            const float* __restrict__ beta, float* __restrict__ a,
                            float* __restrict__ c, float inv_n) {
    int i = threadIdx.x;
    float s = 0.f, s2 = 0.f;
    for (int st = 0; st < stripes; ++st) {
        s += part[st * stride + i];
        s2 += part[st * stride + coff + i];
        part[st * stride + i] = 0.f;
        part[st * stride + coff + i] = 0.f;
    }
    float m = s * inv_n;
    float v = s2 * inv_n - m * m;
    float ai = g[i] * rsqrtf(v + EPS);
    a[i] = ai;
    c[i] = beta[i] - m * ai;
}

// ---------------- pooling + MLP head ----------------

__global__ void k_starts(const int* __restrict__ batch, int* __restrict__ starts) {
    int n = blockIdx.x * 256 + threadIdx.x;
    if (n >= N_NODES) return;
    int b = batch[n];
    int prev = (n == 0) ? -1 : batch[n - 1];
    for (int g = prev + 1; g <= b; ++g) starts[g] = n;
    if (n == N_NODES - 1)
        for (int g = b + 1; g <= N_GRAPHS; ++g) starts[g] = N_NODES;
}

__global__ void k_pool(const h8* __restrict__ x8, const int* __restrict__ starts,
                       const float* __restrict__ a, const float* __restrict__ c,
                       float* __restrict__ pooled) {
    int grp = threadIdx.x >> 4;
    int lane = threadIdx.x & 15;
    int g = blockIdx.x * 8 + grp;
    int beg = starts[g], end = starts[g + 1];
    float s[8] = {};
    for (int n = beg; n < end; ++n) {
        h8 v = x8[(size_t)n * 16 + lane];
#pragma unroll
        for (int i = 0; i < 8; ++i) s[i] += (float)v[i];
    }
    float cnt = (float)(end - beg);
#pragma unroll
    for (int i = 0; i < 8; ++i) {
        int ch = lane * 8 + i;
        pooled[g * D + ch] = fmaf(a[ch], s[i], cnt * c[ch]);
    }
}

__global__ void k_dense_relu(const float* __restrict__ in, const float* __restrict__ W,
                             const float* __restrict__ b, float* __restrict__ out,
                             int K, int N) {
    int row = blockIdx.x;
    int j = threadIdx.x;
    if (j >= N) return;
    float acc = b[j];
    for (int k = 0; k < K; ++k) acc = fmaf(in[row * K + k], W[k * N + j], acc);
    out[row * N + j] = fmaxf(acc, 0.0f);
}

__global__ void k_head_stats(const float* __restrict__ x, float* __restrict__ sums,
                             float* __restrict__ sumsq, int rows) {
    int c = threadIdx.x;
    float s = 0.f, s2 = 0.f;
    int r0 = blockIdx.x * 8;
    int r1 = min(r0 + 8, rows);
    for (int r = r0; r < r1; ++r) {
        float v = x[r * DH + c];
        s += v;
        s2 = fmaf(v, v, s2);
    }
    atomicAdd(&sums[c], s);
    atomicAdd(&sumsq[c], s2);
}

__global__ void k_head_apply(float* __restrict__ x, const float* __restrict__ a,
                             const float* __restrict__ c) {
    int i = blockIdx.x * 256 + threadIdx.x;
    float4 v = ((float4*)x)[i];
    int col = (i << 2) & 255;
    v.x = fmaf(v.x, a[col], c[col]);
    v.y = fmaf(v.y, a[col + 1], c[col + 1]);
    v.z = fmaf(v.z, a[col + 2], c[col + 2]);
    v.w = fmaf(v.w, a[col + 3], c[col + 3]);
    ((float4*)x)[i] = v;
}

__global__ void k_final(const float* __restrict__ h, const float* __restrict__ Wout,
                        const float* __restrict__ bout, float* __restrict__ out) {
    int g = blockIdx.x * 256 + threadIdx.x;
    if (g >= N_GRAPHS) return;
    float acc = bout[0];
    for (int k = 0; k < DH; ++k) acc = fmaf(h[g * DH + k], Wout[k], acc);
    out[g] = acc;
}

// ---------------- launch ----------------

extern "C" void kernel_launch(void* const* d_in, const int* in_sizes, int n_in,
                              void* d_out, int out_size, void* d_ws, size_t ws_size,
                              hipStream_t stream) {
    const float* x = (const float*)d_in[0];
    const int* ei = (const int*)d_in[1];
    const int* batch = (const int*)d_in[2];
    const float* Wc = (const float*)d_in[3];
    const float* bc = (const float*)d_in[4];
    const float* gc = (const float*)d_in[5];
    const float* bec = (const float*)d_in[6];
    const float* Wh0 = (const float*)d_in[7];
    const float* bh0 = (const float*)d_in[8];
    const float* gh0 = (const float*)d_in[9];
    const float* beh0 = (const float*)d_in[10];
    const float* Wh1 = (const float*)d_in[11];
    const float* bh1 = (const float*)d_in[12];
    const float* gh1 = (const float*)d_in[13];
    const float* beh1 = (const float*)d_in[14];
    const float* Wout = (const float*)d_in[15];
    const float* bout = (const float*)d_in[16];
    float* out = (float*)d_out;

    const int* src = ei;
    const int* dst = ei + N_EDGES;

    char* base = (char*)d_ws;
    size_t woff = 0;
    auto alloc = [&](size_t bytes) -> char* {
        char* p = base + woff;
        woff = (woff + bytes + 255) & ~(size_t)255;
        return p;
    };
    _Float16* xh = (_Float16*)alloc(sizeof(_Float16) * (size_t)N_NODES * D);
    _Float16* bufY = (_Float16*)alloc(sizeof(_Float16) * (size_t)N_NODES * D);
    _Float16* bufA = (_Float16*)alloc(sizeof(_Float16) * (size_t)N_NODES * D);
    float* dinv = (float*)alloc(sizeof(float) * N_NODES);
    int* csr = (int*)alloc(sizeof(int) * N_EDGES);
    // single zeroed region: cnt + cursor + part + stats
    char* zero_base = alloc(sizeof(int) * 2 * N_NODES + sizeof(float) * (32 * 256 + 512));
    int* cnt = (int*)zero_base;
    int* cursor = cnt + N_NODES;
    float* part = (float*)(cursor + N_NODES);
    float* stats = part + 32 * 256;
    float* sums = stats;
    float* sumsq = stats + 256;
    size_t zero_bytes = sizeof(int) * 2 * N_NODES + sizeof(float) * (32 * 256 + 512);
    int* offs = (int*)alloc(sizeof(int) * (N_NODES + 1));
    int* bsums = (int*)alloc(sizeof(int) * 512);
    float* avec = (float*)alloc(sizeof(float) * 256);
    float* cvec = (float*)alloc(sizeof(float) * 256);
    _Float16* WT = (_Float16*)alloc(sizeof(_Float16) * D * D);
    float* rvec = (float*)alloc(sizeof(float) * 128);
    int* starts = (int*)alloc(sizeof(int) * (N_GRAPHS + 1));
    float* pooled = (float*)alloc(sizeof(float) * N_GRAPHS * D);
    float* h0 = (float*)alloc(sizeof(float) * N_GRAPHS * DH);
    float* h1 = (float*)alloc(sizeof(float) * N_GRAPHS * DH);

    hipMemsetAsync(zero_base, 0, zero_bytes, stream);

    int nbl = (N_NODES + 255) / 256;
    int fill_grid = ((N_EDGES + FCHUNK - 1) / FCHUNK) * NPART;
    k_count_part<<<fill_grid, 256, 0, stream>>>(dst, cnt);
    k_scan1<<<nbl, 256, 0, stream>>>(cnt, offs, bsums, dinv, N_NODES);
    k_scan2<<<1, 512, 0, stream>>>(bsums, nbl);
    k_scan3<<<nbl, 256, 0, stream>>>(offs, bsums, N_NODES);
    k_fill_part<<<fill_grid, 256, 0, stream>>>(src, dst, offs, cursor, csr);
    k_cast<<<(N_NODES * D / 8 + 255) / 256, 256, 0, stream>>>((const float4*)x,
                                                              (h8*)xh, N_NODES * D / 8);

    const _Float16* cur_in = xh;
    int gemm_grid = (N_NODES + 63) / 64;
    for (int layer = 0; layer < 3; ++layer) {
        k_fold<<<65, 256, 0, stream>>>(Wc + layer * D * D, avec, cvec, layer > 0, WT, rvec);
        k_gemm<<<gemm_grid, 256, 0, stream>>>(cur_in, WT, rvec, bufY, N_NODES);
        k_aggregate<<<N_NODES / 16, 256, 0, stream>>>(
            (const h8*)bufY, offs, csr, dinv, bc + layer * D, (h8*)bufA, part);
        k_bn_coeffs<<<1, 128, 0, stream>>>(part, 32, 256, 128, gc + layer * D,
                                           bec + layer * D, avec, cvec, 1.0f / N_NODES);
        cur_in = bufA;
    }

    k_starts<<<nbl, 256, 0, stream>>>(batch, starts);
    k_pool<<<N_GRAPHS / 8, 128, 0, stream>>>((const h8*)bufA, starts, avec, cvec, pooled);

    k_dense_relu<<<N_GRAPHS, 256, 0, stream>>>(pooled, Wh0, bh0, h0, D, DH);
    k_head_stats<<<64, 256, 0, stream>>>(h0, sums, sumsq, N_GRAPHS);
    k_bn_coeffs<<<1, 256, 0, stream>>>(stats, 1, 512, 256, gh0, beh0, avec, cvec,
                                       1.0f / N_GRAPHS);
    k_head_apply<<<N_GRAPHS * DH / 4 / 256, 256, 0, stream>>>(h0, avec, cvec);

    k_dense_relu<<<N_GRAPHS, 256, 0, stream>>>(h0, Wh1, bh1, h1, DH, DH);
    k_head_stats<<<64, 256, 0, stream>>>(h1, sums, sumsq, N_GRAPHS);
    k_bn_coeffs<<<1, 256, 0, stream>>>(stats, 1, 512, 256, gh1, beh1, avec, cvec,
                                       1.0f / N_GRAPHS);
    k_head_apply<<<N_GRAPHS * DH / 4 / 256, 256, 0, stream>>>(h1, avec, cvec);

    k_final<<<2, 256, 0, stream>>>(h1, Wout, bout, out);
}

// Round 6
// 704.143 us; speedup vs baseline: 1.3203x; 1.1878x over previous
//
#include <hip/hip_runtime.h>

#define N_NODES 100000
#define N_EDGES 1600000
#define D 128
#define DH 256
#define N_GRAPHS 512
#define EPS 1e-5f
#define NPART 8
#define PSIZE 12500      // N_NODES / NPART
#define FCHUNK 4096      // edges per fill chunk

typedef _Float16 h8 __attribute__((ext_vector_type(8)));
typedef float f4 __attribute__((ext_vector_type(4)));

// ---------------- preprocessing ----------------

// XCD-partitioned degree count: block handles partition (blockIdx&7) only
__global__ void k_count_part(const int* __restrict__ dst, int* __restrict__ cnt) {
    int part = blockIdx.x & 7;
    int base = (blockIdx.x >> 3) * FCHUNK;
    int lo = part * PSIZE, hi = lo + PSIZE;
    int lim = min(FCHUNK, N_EDGES - base);
    for (int i = threadIdx.x; i < lim; i += 256) {
        int d = dst[base + i];
        if (d >= lo && d < hi) atomicAdd(&cnt[d], 1);
    }
}

// scan within 256-blocks; also emits dinv = rsqrt(cnt+1)
__global__ void k_scan1(const int* __restrict__ in, int* __restrict__ out,
                        int* __restrict__ bsums, float* __restrict__ dinv, int n) {
    __shared__ int tmp[256];
    int gid = blockIdx.x * 256 + threadIdx.x;
    int v = (gid < n) ? in[gid] : 0;
    if (gid < n) dinv[gid] = rsqrtf((float)(v + 1));
    tmp[threadIdx.x] = v;
    __syncthreads();
    for (int off = 1; off < 256; off <<= 1) {
        int t = (threadIdx.x >= off) ? tmp[threadIdx.x - off] : 0;
        __syncthreads();
        tmp[threadIdx.x] += t;
        __syncthreads();
    }
    if (gid < n) out[gid] = tmp[threadIdx.x] - v;
    if (threadIdx.x == 255) bsums[blockIdx.x] = tmp[255];
}

__global__ void k_scan2(int* __restrict__ bsums, int nb) {
    __shared__ int tmp[512];
    int v = (threadIdx.x < nb) ? bsums[threadIdx.x] : 0;
    tmp[threadIdx.x] = v;
    __syncthreads();
    for (int off = 1; off < 512; off <<= 1) {
        int t = (threadIdx.x >= off) ? tmp[threadIdx.x - off] : 0;
        __syncthreads();
        tmp[threadIdx.x] += t;
        __syncthreads();
    }
    if (threadIdx.x < nb) bsums[threadIdx.x] = tmp[threadIdx.x] - v;
}

__global__ void k_scan3(int* __restrict__ out, const int* __restrict__ bsums, int n) {
    int gid = blockIdx.x * 256 + threadIdx.x;
    if (gid < n) out[gid] += bsums[blockIdx.x];
    if (gid == 0) out[n] = N_EDGES;
}

// XCD-partitioned CSR scatter
__global__ void k_fill_part(const int* __restrict__ src, const int* __restrict__ dst,
                            const int* __restrict__ offs, int* __restrict__ cursor,
                            int* __restrict__ csr) {
    int part = blockIdx.x & 7;
    int base = (blockIdx.x >> 3) * FCHUNK;
    int lo = part * PSIZE, hi = lo + PSIZE;
    int lim = min(FCHUNK, N_EDGES - base);
    for (int i = threadIdx.x; i < lim; i += 256) {
        int d = dst[base + i];
        if (d >= lo && d < hi) {
            int pos = offs[d] + atomicAdd(&cursor[d], 1);
            csr[pos] = src[base + i];
        }
    }
}

// cast fp32 x -> fp16 (half8 per thread)
__global__ void k_cast(const float4* __restrict__ x4, h8* __restrict__ xh, int n8) {
    int i = blockIdx.x * 256 + threadIdx.x;
    if (i >= n8) return;
    float4 a = x4[2 * i], b = x4[2 * i + 1];
    h8 o;
    o[0] = (_Float16)a.x; o[1] = (_Float16)a.y; o[2] = (_Float16)a.z; o[3] = (_Float16)a.w;
    o[4] = (_Float16)b.x; o[5] = (_Float16)b.y; o[6] = (_Float16)b.z; o[7] = (_Float16)b.w;
    xh[i] = o;
}

// BN fold merged: blocks 0..63: WT[n][k] = a[k]*W[k][n] (fp16); block 64: r[j]
__global__ void k_fold(const float* __restrict__ W, const float* __restrict__ a,
                       const float* __restrict__ c, int use_bn,
                       _Float16* __restrict__ WT, float* __restrict__ r) {
    if (blockIdx.x < 64) {
        int idx = blockIdx.x * 256 + threadIdx.x;
        int n = idx >> 7, k = idx & 127;
        float s = use_bn ? a[k] : 1.0f;
        WT[idx] = (_Float16)(s * W[k * D + n]);
    } else if (threadIdx.x < 128) {
        int j = threadIdx.x;
        float s = 0.f;
        if (use_bn)
            for (int k = 0; k < D; ++k) s = fmaf(c[k], W[k * D + j], s);
        r[j] = s;
    }
}

// ---------------- MFMA GEMM: Y[nrows,128] = X @ W + r, fp16 in/out ----------
__global__ __launch_bounds__(256) void k_gemm(const _Float16* __restrict__ X,
                                              const _Float16* __restrict__ WT,
                                              const float* __restrict__ radd,
                                              _Float16* __restrict__ Y, int nrows) {
    __shared__ _Float16 Wl[128][136];
    __shared__ _Float16 Yl[64][136];
    int t = threadIdx.x;
    {
        const h8* src = (const h8*)WT;
        for (int i = t; i < 128 * 16; i += 256) {
            int r = i >> 4, c = i & 15;
            *(h8*)&Wl[r][c * 8] = src[i];
        }
    }
    int wave = t >> 6;
    int lane = t & 63;
    int l15 = lane & 15;
    int quad = lane >> 4;
    int rowblk = blockIdx.x * 64;
    int row0 = rowblk + wave * 16;

    h8 zero8;
#pragma unroll
    for (int j = 0; j < 8; ++j) zero8[j] = (_Float16)0;

    h8 a[4];
    bool inb = (row0 + l15) < nrows;
    const _Float16* xrow = X + (size_t)(row0 + l15) * D + quad * 8;
#pragma unroll
    for (int kt = 0; kt < 4; ++kt) a[kt] = inb ? *(const h8*)(xrow + kt * 32) : zero8;

    __syncthreads();

    f4 acc[8];
#pragma unroll
    for (int n = 0; n < 8; ++n) {
        acc[n][0] = 0.f; acc[n][1] = 0.f; acc[n][2] = 0.f; acc[n][3] = 0.f;
#pragma unroll
        for (int kt = 0; kt < 4; ++kt) {
            h8 b = *(const h8*)&Wl[n * 16 + l15][kt * 32 + quad * 8];
            acc[n] = __builtin_amdgcn_mfma_f32_16x16x32_f16(a[kt], b, acc[n], 0, 0, 0);
        }
    }
#pragma unroll
    for (int n = 0; n < 8; ++n) {
        float r = radd[n * 16 + l15];
#pragma unroll
        for (int i = 0; i < 4; ++i)
            Yl[wave * 16 + quad * 4 + i][n * 16 + l15] = (_Float16)(acc[n][i] + r);
    }
    __syncthreads();
    for (int i = t; i < 64 * 16; i += 256) {
        int r = i >> 4, c = i & 15;
        if (rowblk + r < nrows)
            *(h8*)&Y[(size_t)(rowblk + r) * D + c * 8] = *(h8*)&Yl[r][c * 8];
    }
}

// ---------------- aggregate + relu + fused BN partial stats ----------------
__global__ __launch_bounds__(256) void k_aggregate(const h8* __restrict__ Y8,
                                                   const int* __restrict__ offs,
                                                   const int* __restrict__ csr,
                                                   const float* __restrict__ dinv,
                                                   const float* __restrict__ bias,
                                                   h8* __restrict__ A8,
                                                   float* __restrict__ part) {
    int grp = threadIdx.x >> 4;
    int lane = threadIdx.x & 15;
    int node = blockIdx.x * 16 + grp;
    int beg = offs[node], end = offs[node + 1];
    float dn = dinv[node];
    float acc[8];
    h8 y = Y8[(size_t)node * 16 + lane];
#pragma unroll
    for (int i = 0; i < 8; ++i) acc[i] = dn * (float)y[i];
    for (int e = beg; e < end; ++e) {
        int s = csr[e];
        float ds = dinv[s];
        h8 v = Y8[(size_t)s * 16 + lane];
#pragma unroll
        for (int i = 0; i < 8; ++i) acc[i] = fmaf(ds, (float)v[i], acc[i]);
    }
    __shared__ float red[16][128];
    h8 o;
#pragma unroll
    for (int i = 0; i < 8; ++i) {
        float v = fmaxf(fmaf(acc[i], dn, bias[lane * 8 + i]), 0.f);
        o[i] = (_Float16)v;
        red[grp][lane * 8 + i] = v;
    }
    A8[(size_t)node * 16 + lane] = o;
    __syncthreads();
    if (threadIdx.x < 128) {
        int c = threadIdx.x;
        float s = 0.f, s2 = 0.f;
#pragma unroll
        for (int g = 0; g < 16; ++g) {
            float v = red[g][c];
            s += v;
            s2 = fmaf(v, v, s2);
        }
        float* p = part + (size_t)(blockIdx.x & 31) * 256;
        atomicAdd(&p[c], s);
        atomicAdd(&p[128 + c], s2);
    }
}

// BN coeffs from striped partials; re-zeroes partials for the next user
__global__ void k_bn_coeffs(float* __restrict__ part, int stripes, int stride,
                            int coff, const float* __restrict__ g,
                            const float* __restrict__ beta, float* __restrict__ a,
                            float* __restrict__ c, float inv_n) {
    int i = threadIdx.x;
    float s = 0.f, s2 = 0.f;
    for (int st = 0; st < stripes; ++st) {
        s += part[st * stride + i];
        s2 += part[st * stride + coff + i];
        part[st * stride + i] = 0.f;
        part[st * stride + coff + i] = 0.f;
    }
    float m = s * inv_n;
    float v = s2 * inv_n - m * m;
    float ai = g[i] * rsqrtf(v + EPS);
    a[i] = ai;
    c[i] = beta[i] - m * ai;
}

// ---------------- pooling + MLP head ----------------

__global__ void k_starts(const int* __restrict__ batch, int* __restrict__ starts) {
    int n = blockIdx.x * 256 + threadIdx.x;
    if (n >= N_NODES) return;
    int b = batch[n];
    int prev = (n == 0) ? -1 : batch[n - 1];
    for (int g = prev + 1; g <= b; ++g) starts[g] = n;
    if (n == N_NODES - 1)
        for (int g = b + 1; g <= N_GRAPHS; ++g) starts[g] = N_NODES;
}

__global__ void k_pool(const h8* __restrict__ x8, const int* __restrict__ starts,
                       const float* __restrict__ a, const float* __restrict__ c,
                       float* __restrict__ pooled) {
    int grp = threadIdx.x >> 4;
    int lane = threadIdx.x & 15;
    int g = blockIdx.x * 8 + grp;
    int beg = starts[g], end = starts[g + 1];
    float s[8] = {};
    for (int n = beg; n < end; ++n) {
        h8 v = x8[(size_t)n * 16 + lane];
#pragma unroll
        for (int i = 0; i < 8; ++i) s[i] += (float)v[i];
    }
    float cnt = (float)(end - beg);
#pragma unroll
    for (int i = 0; i < 8; ++i) {
        int ch = lane * 8 + i;
        pooled[g * D + ch] = fmaf(a[ch], s[i], cnt * c[ch]);
    }
}

// dense + relu, compile-time K, N=256: full unroll -> deep load pipeline
template <int K>
__global__ __launch_bounds__(256) void k_dense(const float* __restrict__ in,
                                               const float* __restrict__ W,
                                               const float* __restrict__ b,
                                               float* __restrict__ out) {
    __shared__ float inl[K];
    int row = blockIdx.x;
    for (int k = threadIdx.x; k < K; k += 256) inl[k] = in[row * K + k];
    __syncthreads();
    int j = threadIdx.x;
    float acc = b[j];
#pragma unroll
    for (int k = 0; k < K; ++k) acc = fmaf(inl[k], W[k * 256 + j], acc);
    out[row * 256 + j] = fmaxf(acc, 0.0f);
}

__global__ void k_head_stats(const float* __restrict__ x, float* __restrict__ sums,
                             float* __restrict__ sumsq, int rows) {
    int c = threadIdx.x;
    float s = 0.f, s2 = 0.f;
    int r0 = blockIdx.x * 8;
    int r1 = min(r0 + 8, rows);
    for (int r = r0; r < r1; ++r) {
        float v = x[r * DH + c];
        s += v;
        s2 = fmaf(v, v, s2);
    }
    atomicAdd(&sums[c], s);
    atomicAdd(&sumsq[c], s2);
}

__global__ void k_head_apply(float* __restrict__ x, const float* __restrict__ a,
                             const float* __restrict__ c) {
    int i = blockIdx.x * 256 + threadIdx.x;
    float4 v = ((float4*)x)[i];
    int col = (i << 2) & 255;
    v.x = fmaf(v.x, a[col], c[col]);
    v.y = fmaf(v.y, a[col + 1], c[col + 1]);
    v.z = fmaf(v.z, a[col + 2], c[col + 2]);
    v.w = fmaf(v.w, a[col + 3], c[col + 3]);
    ((float4*)x)[i] = v;
}

// final dot: 4 graphs/block, 64 lanes/graph, float4 + wave reduce
__global__ void k_final(const float* __restrict__ h, const float* __restrict__ Wout,
                        const float* __restrict__ bout, float* __restrict__ out) {
    int g = blockIdx.x * 4 + (threadIdx.x >> 6);
    int lane = threadIdx.x & 63;
    float4 v = ((const float4*)(h + g * DH))[lane];
    float4 w = ((const float4*)Wout)[lane];
    float acc = v.x * w.x + v.y * w.y + v.z * w.z + v.w * w.w;
#pragma unroll
    for (int off = 32; off; off >>= 1) acc += __shfl_down(acc, off, 64);
    if (lane == 0) out[g] = acc + bout[0];
}

// ---------------- launch ----------------

extern "C" void kernel_launch(void* const* d_in, const int* in_sizes, int n_in,
                              void* d_out, int out_size, void* d_ws, size_t ws_size,
                              hipStream_t stream) {
    const float* x = (const float*)d_in[0];
    const int* ei = (const int*)d_in[1];
    const int* batch = (const int*)d_in[2];
    const float* Wc = (const float*)d_in[3];
    const float* bc = (const float*)d_in[4];
    const float* gc = (const float*)d_in[5];
    const float* bec = (const float*)d_in[6];
    const float* Wh0 = (const float*)d_in[7];
    const float* bh0 = (const float*)d_in[8];
    const float* gh0 = (const float*)d_in[9];
    const float* beh0 = (const float*)d_in[10];
    const float* Wh1 = (const float*)d_in[11];
    const float* bh1 = (const float*)d_in[12];
    const float* gh1 = (const float*)d_in[13];
    const float* beh1 = (const float*)d_in[14];
    const float* Wout = (const float*)d_in[15];
    const float* bout = (const float*)d_in[16];
    float* out = (float*)d_out;

    const int* src = ei;
    const int* dst = ei + N_EDGES;

    char* base = (char*)d_ws;
    size_t woff = 0;
    auto alloc = [&](size_t bytes) -> char* {
        char* p = base + woff;
        woff = (woff + bytes + 255) & ~(size_t)255;
        return p;
    };
    _Float16* xh = (_Float16*)alloc(sizeof(_Float16) * (size_t)N_NODES * D);
    _Float16* bufY = (_Float16*)alloc(sizeof(_Float16) * (size_t)N_NODES * D);
    _Float16* bufA = (_Float16*)alloc(sizeof(_Float16) * (size_t)N_NODES * D);
    float* dinv = (float*)alloc(sizeof(float) * N_NODES);
    int* csr = (int*)alloc(sizeof(int) * N_EDGES);
    // single zeroed region: cnt + cursor + part + stats
    char* zero_base = alloc(sizeof(int) * 2 * N_NODES + sizeof(float) * (32 * 256 + 512));
    int* cnt = (int*)zero_base;
    int* cursor = cnt + N_NODES;
    float* part = (float*)(cursor + N_NODES);
    float* stats = part + 32 * 256;
    float* sums = stats;
    float* sumsq = stats + 256;
    size_t zero_bytes = sizeof(int) * 2 * N_NODES + sizeof(float) * (32 * 256 + 512);
    int* offs = (int*)alloc(sizeof(int) * (N_NODES + 1));
    int* bsums = (int*)alloc(sizeof(int) * 512);
    float* avec = (float*)alloc(sizeof(float) * 256);
    float* cvec = (float*)alloc(sizeof(float) * 256);
    _Float16* WT = (_Float16*)alloc(sizeof(_Float16) * D * D);
    float* rvec = (float*)alloc(sizeof(float) * 128);
    int* starts = (int*)alloc(sizeof(int) * (N_GRAPHS + 1));
    float* pooled = (float*)alloc(sizeof(float) * N_GRAPHS * D);
    float* h0 = (float*)alloc(sizeof(float) * N_GRAPHS * DH);
    float* h1 = (float*)alloc(sizeof(float) * N_GRAPHS * DH);

    hipMemsetAsync(zero_base, 0, zero_bytes, stream);

    int nbl = (N_NODES + 255) / 256;
    int fill_grid = ((N_EDGES + FCHUNK - 1) / FCHUNK) * NPART;
    k_count_part<<<fill_grid, 256, 0, stream>>>(dst, cnt);
    k_scan1<<<nbl, 256, 0, stream>>>(cnt, offs, bsums, dinv, N_NODES);
    k_scan2<<<1, 512, 0, stream>>>(bsums, nbl);
    k_scan3<<<nbl, 256, 0, stream>>>(offs, bsums, N_NODES);
    k_fill_part<<<fill_grid, 256, 0, stream>>>(src, dst, offs, cursor, csr);
    k_cast<<<(N_NODES * D / 8 + 255) / 256, 256, 0, stream>>>((const float4*)x,
                                                              (h8*)xh, N_NODES * D / 8);

    const _Float16* cur_in = xh;
    int gemm_grid = (N_NODES + 63) / 64;
    for (int layer = 0; layer < 3; ++layer) {
        k_fold<<<65, 256, 0, stream>>>(Wc + layer * D * D, avec, cvec, layer > 0, WT, rvec);
        k_gemm<<<gemm_grid, 256, 0, stream>>>(cur_in, WT, rvec, bufY, N_NODES);
        k_aggregate<<<N_NODES / 16, 256, 0, stream>>>(
            (const h8*)bufY, offs, csr, dinv, bc + layer * D, (h8*)bufA, part);
        k_bn_coeffs<<<1, 128, 0, stream>>>(part, 32, 256, 128, gc + layer * D,
                                           bec + layer * D, avec, cvec, 1.0f / N_NODES);
        cur_in = bufA;
    }

    k_starts<<<nbl, 256, 0, stream>>>(batch, starts);
    k_pool<<<N_GRAPHS / 8, 128, 0, stream>>>((const h8*)bufA, starts, avec, cvec, pooled);

    k_dense<128><<<N_GRAPHS, 256, 0, stream>>>(pooled, Wh0, bh0, h0);
    k_head_stats<<<64, 256, 0, stream>>>(h0, sums, sumsq, N_GRAPHS);
    k_bn_coeffs<<<1, 256, 0, stream>>>(stats, 1, 512, 256, gh0, beh0, avec, cvec,
                                       1.0f / N_GRAPHS);
    k_head_apply<<<N_GRAPHS * DH / 4 / 256, 256, 0, stream>>>(h0, avec, cvec);

    k_dense<256><<<N_GRAPHS, 256, 0, stream>>>(h0, Wh1, bh1, h1);
    k_head_stats<<<64, 256, 0, stream>>>(h1, sums, sumsq, N_GRAPHS);
    k_bn_coeffs<<<1, 256, 0, stream>>>(stats, 1, 512, 256, gh1, beh1, avec, cvec,
                                       1.0f / N_GRAPHS);
    k_head_apply<<<N_GRAPHS * DH / 4 / 256, 256, 0, stream>>>(h1, avec, cvec);

    k_final<<<N_GRAPHS / 4, 256, 0, stream>>>(h1, Wout, bout, out);
}

// Round 7
// 623.819 us; speedup vs baseline: 1.4903x; 1.1288x over previous
//
#include <hip/hip_runtime.h>

#define N_NODES 100000
#define N_EDGES 1600000
#define D 128
#define DH 256
#define N_GRAPHS 512
#define EPS 1e-5f
#define NPART 8
#define PSIZE 12500      // N_NODES / NPART
#define FCHUNK 4096      // edges per fill chunk

typedef _Float16 h8 __attribute__((ext_vector_type(8)));
typedef float f4 __attribute__((ext_vector_type(4)));

// ---------------- preprocessing ----------------

// XCD-partitioned degree count: block handles partition (blockIdx&7) only
__global__ void k_count_part(const int* __restrict__ dst, int* __restrict__ cnt) {
    int part = blockIdx.x & 7;
    int base = (blockIdx.x >> 3) * FCHUNK;
    int lo = part * PSIZE, hi = lo + PSIZE;
    int lim = min(FCHUNK, N_EDGES - base);
    for (int i = threadIdx.x; i < lim; i += 256) {
        int d = dst[base + i];
        if (d >= lo && d < hi) atomicAdd(&cnt[d], 1);
    }
}

// scan within 256-blocks; also emits dinv = rsqrt(cnt+1)
__global__ void k_scan1(const int* __restrict__ in, int* __restrict__ out,
                        int* __restrict__ bsums, float* __restrict__ dinv, int n) {
    __shared__ int tmp[256];
    int gid = blockIdx.x * 256 + threadIdx.x;
    int v = (gid < n) ? in[gid] : 0;
    if (gid < n) dinv[gid] = rsqrtf((float)(v + 1));
    tmp[threadIdx.x] = v;
    __syncthreads();
    for (int off = 1; off < 256; off <<= 1) {
        int t = (threadIdx.x >= off) ? tmp[threadIdx.x - off] : 0;
        __syncthreads();
        tmp[threadIdx.x] += t;
        __syncthreads();
    }
    if (gid < n) out[gid] = tmp[threadIdx.x] - v;
    if (threadIdx.x == 255) bsums[blockIdx.x] = tmp[255];
}

__global__ void k_scan2(int* __restrict__ bsums, int nb) {
    __shared__ int tmp[512];
    int v = (threadIdx.x < nb) ? bsums[threadIdx.x] : 0;
    tmp[threadIdx.x] = v;
    __syncthreads();
    for (int off = 1; off < 512; off <<= 1) {
        int t = (threadIdx.x >= off) ? tmp[threadIdx.x - off] : 0;
        __syncthreads();
        tmp[threadIdx.x] += t;
        __syncthreads();
    }
    if (threadIdx.x < nb) bsums[threadIdx.x] = tmp[threadIdx.x] - v;
}

__global__ void k_scan3(int* __restrict__ out, const int* __restrict__ bsums, int n) {
    int gid = blockIdx.x * 256 + threadIdx.x;
    if (gid < n) out[gid] += bsums[blockIdx.x];
    if (gid == 0) out[n] = N_EDGES;
}

// XCD-partitioned CSR scatter
__global__ void k_fill_part(const int* __restrict__ src, const int* __restrict__ dst,
                            const int* __restrict__ offs, int* __restrict__ cursor,
                            int* __restrict__ csr) {
    int part = blockIdx.x & 7;
    int base = (blockIdx.x >> 3) * FCHUNK;
    int lo = part * PSIZE, hi = lo + PSIZE;
    int lim = min(FCHUNK, N_EDGES - base);
    for (int i = threadIdx.x; i < lim; i += 256) {
        int d = dst[base + i];
        if (d >= lo && d < hi) {
            int pos = offs[d] + atomicAdd(&cursor[d], 1);
            csr[pos] = src[base + i];
        }
    }
}

// BN fold merged: blocks 0..63: WT[n][k] = a[k]*W[k][n] (fp16); block 64: r[j]
__global__ void k_fold(const float* __restrict__ W, const float* __restrict__ a,
                       const float* __restrict__ c, int use_bn,
                       _Float16* __restrict__ WT, float* __restrict__ r) {
    if (blockIdx.x < 64) {
        int idx = blockIdx.x * 256 + threadIdx.x;
        int n = idx >> 7, k = idx & 127;
        float s = use_bn ? a[k] : 1.0f;
        WT[idx] = (_Float16)(s * W[k * D + n]);
    } else if (threadIdx.x < 128) {
        int j = threadIdx.x;
        float s = 0.f;
        if (use_bn)
            for (int k = 0; k < D; ++k) s = fmaf(c[k], W[k * D + j], s);
        r[j] = s;
    }
}

// ---------------- MFMA GEMM: Y[nrows,128] = X @ W + r, fp16 out -------------
// F32IN: X is fp32 (layer 0, converts in-register); else fp16
template <bool F32IN>
__global__ __launch_bounds__(256) void k_gemm(const void* __restrict__ Xv,
                                              const _Float16* __restrict__ WT,
                                              const float* __restrict__ radd,
                                              _Float16* __restrict__ Y, int nrows) {
    __shared__ _Float16 Wl[128][136];
    __shared__ _Float16 Yl[64][136];
    int t = threadIdx.x;
    {
        const h8* src = (const h8*)WT;
        for (int i = t; i < 128 * 16; i += 256) {
            int r = i >> 4, c = i & 15;
            *(h8*)&Wl[r][c * 8] = src[i];
        }
    }
    int wave = t >> 6;
    int lane = t & 63;
    int l15 = lane & 15;
    int quad = lane >> 4;
    int rowblk = blockIdx.x * 64;
    int row0 = rowblk + wave * 16;

    h8 zero8;
#pragma unroll
    for (int j = 0; j < 8; ++j) zero8[j] = (_Float16)0;

    h8 a[4];
    bool inb = (row0 + l15) < nrows;
#pragma unroll
    for (int kt = 0; kt < 4; ++kt) a[kt] = zero8;
    if (inb) {
        if constexpr (F32IN) {
            const float* xrow = (const float*)Xv + (size_t)(row0 + l15) * D + quad * 8;
#pragma unroll
            for (int kt = 0; kt < 4; ++kt) {
                float4 u = *(const float4*)(xrow + kt * 32);
                float4 w = *(const float4*)(xrow + kt * 32 + 4);
                h8 o;
                o[0] = (_Float16)u.x; o[1] = (_Float16)u.y;
                o[2] = (_Float16)u.z; o[3] = (_Float16)u.w;
                o[4] = (_Float16)w.x; o[5] = (_Float16)w.y;
                o[6] = (_Float16)w.z; o[7] = (_Float16)w.w;
                a[kt] = o;
            }
        } else {
            const _Float16* xrow = (const _Float16*)Xv + (size_t)(row0 + l15) * D + quad * 8;
#pragma unroll
            for (int kt = 0; kt < 4; ++kt) a[kt] = *(const h8*)(xrow + kt * 32);
        }
    }

    __syncthreads();

    f4 acc[8];
#pragma unroll
    for (int n = 0; n < 8; ++n) {
        acc[n][0] = 0.f; acc[n][1] = 0.f; acc[n][2] = 0.f; acc[n][3] = 0.f;
#pragma unroll
        for (int kt = 0; kt < 4; ++kt) {
            h8 b = *(const h8*)&Wl[n * 16 + l15][kt * 32 + quad * 8];
            acc[n] = __builtin_amdgcn_mfma_f32_16x16x32_f16(a[kt], b, acc[n], 0, 0, 0);
        }
    }
#pragma unroll
    for (int n = 0; n < 8; ++n) {
        float r = radd[n * 16 + l15];
#pragma unroll
        for (int i = 0; i < 4; ++i)
            Yl[wave * 16 + quad * 4 + i][n * 16 + l15] = (_Float16)(acc[n][i] + r);
    }
    __syncthreads();
    for (int i = t; i < 64 * 16; i += 256) {
        int r = i >> 4, c = i & 15;
        if (rowblk + r < nrows)
            *(h8*)&Y[(size_t)(rowblk + r) * D + c * 8] = *(h8*)&Yl[r][c * 8];
    }
}

// ---------------- aggregate + relu + fused BN partial stats ----------------
__global__ __launch_bounds__(256) void k_aggregate(const h8* __restrict__ Y8,
                                                   const int* __restrict__ offs,
                                                   const int* __restrict__ csr,
                                                   const float* __restrict__ dinv,
                                                   const float* __restrict__ bias,
                                                   h8* __restrict__ A8,
                                                   float* __restrict__ part) {
    int grp = threadIdx.x >> 4;
    int lane = threadIdx.x & 15;
    int node = blockIdx.x * 16 + grp;
    int beg = offs[node], end = offs[node + 1];
    float dn = dinv[node];
    float acc[8];
    h8 y = Y8[(size_t)node * 16 + lane];
#pragma unroll
    for (int i = 0; i < 8; ++i) acc[i] = dn * (float)y[i];
    for (int e = beg; e < end; ++e) {
        int s = csr[e];
        float ds = dinv[s];
        h8 v = Y8[(size_t)s * 16 + lane];
#pragma unroll
        for (int i = 0; i < 8; ++i) acc[i] = fmaf(ds, (float)v[i], acc[i]);
    }
    __shared__ float red[16][128];
    h8 o;
#pragma unroll
    for (int i = 0; i < 8; ++i) {
        float v = fmaxf(fmaf(acc[i], dn, bias[lane * 8 + i]), 0.f);
        o[i] = (_Float16)v;
        red[grp][lane * 8 + i] = v;
    }
    A8[(size_t)node * 16 + lane] = o;
    __syncthreads();
    if (threadIdx.x < 128) {
        int c = threadIdx.x;
        float s = 0.f, s2 = 0.f;
#pragma unroll
        for (int g = 0; g < 16; ++g) {
            float v = red[g][c];
            s += v;
            s2 = fmaf(v, v, s2);
        }
        float* p = part + (size_t)(blockIdx.x & 31) * 256;
        atomicAdd(&p[c], s);
        atomicAdd(&p[128 + c], s2);
    }
}

// BN coeffs from striped partials; re-zeroes partials for the next user
__global__ void k_bn_coeffs(float* __restrict__ part, int stripes, int stride,
                            int coff, const float* __restrict__ g,
                            const float* __restrict__ beta, float* __restrict__ a,
                            float* __restrict__ c, float inv_n) {
    int i = threadIdx.x;
    float s = 0.f, s2 = 0.f;
    for (int st = 0; st < stripes; ++st) {
        s += part[st * stride + i];
        s2 += part[st * stride + coff + i];
        part[st * stride + i] = 0.f;
        part[st * stride + coff + i] = 0.f;
    }
    float m = s * inv_n;
    float v = s2 * inv_n - m * m;
    float ai = g[i] * rsqrtf(v + EPS);
    a[i] = ai;
    c[i] = beta[i] - m * ai;
}

// ---------------- pooling + MLP head ----------------

__global__ void k_starts(const int* __restrict__ batch, int* __restrict__ starts) {
    int n = blockIdx.x * 256 + threadIdx.x;
    if (n >= N_NODES) return;
    int b = batch[n];
    int prev = (n == 0) ? -1 : batch[n - 1];
    for (int g = prev + 1; g <= b; ++g) starts[g] = n;
    if (n == N_NODES - 1)
        for (int g = b + 1; g <= N_GRAPHS; ++g) starts[g] = N_NODES;
}

// one block per graph: 16 row-groups x 16 lanes, LDS reduce
__global__ __launch_bounds__(256) void k_pool(const h8* __restrict__ x8,
                                              const int* __restrict__ starts,
                                              const float* __restrict__ a,
                                              const float* __restrict__ c,
                                              float* __restrict__ pooled) {
    int g = blockIdx.x;
    int grp = threadIdx.x >> 4;
    int lane = threadIdx.x & 15;
    int beg = starts[g], end = starts[g + 1];
    float s[8] = {};
    for (int n = beg + grp; n < end; n += 16) {
        h8 v = x8[(size_t)n * 16 + lane];
#pragma unroll
        for (int i = 0; i < 8; ++i) s[i] += (float)v[i];
    }
    __shared__ float red[16][128];
#pragma unroll
    for (int i = 0; i < 8; ++i) red[grp][lane * 8 + i] = s[i];
    __syncthreads();
    if (threadIdx.x < 128) {
        int ch = threadIdx.x;
        float t = 0.f;
#pragma unroll
        for (int gg = 0; gg < 16; ++gg) t += red[gg][ch];
        float cnt = (float)(end - beg);
        pooled[g * D + ch] = fmaf(a[ch], t, cnt * c[ch]);
    }
}

// dense + relu, compile-time K, N=256: full unroll -> deep load pipeline
template <int K>
__global__ __launch_bounds__(256) void k_dense(const float* __restrict__ in,
                                               const float* __restrict__ W,
                                               const float* __restrict__ b,
                                               float* __restrict__ out) {
    __shared__ float inl[K];
    int row = blockIdx.x;
    for (int k = threadIdx.x; k < K; k += 256) inl[k] = in[row * K + k];
    __syncthreads();
    int j = threadIdx.x;
    float acc = b[j];
#pragma unroll
    for (int k = 0; k < K; ++k) acc = fmaf(inl[k], W[k * 256 + j], acc);
    out[row * 256 + j] = fmaxf(acc, 0.0f);
}

__global__ void k_head_stats(const float* __restrict__ x, float* __restrict__ sums,
                             float* __restrict__ sumsq, int rows) {
    int c = threadIdx.x;
    float s = 0.f, s2 = 0.f;
    int r0 = blockIdx.x * 8;
    int r1 = min(r0 + 8, rows);
    for (int r = r0; r < r1; ++r) {
        float v = x[r * DH + c];
        s += v;
        s2 = fmaf(v, v, s2);
    }
    atomicAdd(&sums[c], s);
    atomicAdd(&sumsq[c], s2);
}

__global__ void k_head_apply(float* __restrict__ x, const float* __restrict__ a,
                             const float* __restrict__ c) {
    int i = blockIdx.x * 256 + threadIdx.x;
    float4 v = ((float4*)x)[i];
    int col = (i << 2) & 255;
    v.x = fmaf(v.x, a[col], c[col]);
    v.y = fmaf(v.y, a[col + 1], c[col + 1]);
    v.z = fmaf(v.z, a[col + 2], c[col + 2]);
    v.w = fmaf(v.w, a[col + 3], c[col + 3]);
    ((float4*)x)[i] = v;
}

// final dot: 4 graphs/block, 64 lanes/graph, float4 + wave reduce
__global__ void k_final(const float* __restrict__ h, const float* __restrict__ Wout,
                        const float* __restrict__ bout, float* __restrict__ out) {
    int g = blockIdx.x * 4 + (threadIdx.x >> 6);
    int lane = threadIdx.x & 63;
    float4 v = ((const float4*)(h + g * DH))[lane];
    float4 w = ((const float4*)Wout)[lane];
    float acc = v.x * w.x + v.y * w.y + v.z * w.z + v.w * w.w;
#pragma unroll
    for (int off = 32; off; off >>= 1) acc += __shfl_down(acc, off, 64);
    if (lane == 0) out[g] = acc + bout[0];
}

// ---------------- launch ----------------

extern "C" void kernel_launch(void* const* d_in, const int* in_sizes, int n_in,
                              void* d_out, int out_size, void* d_ws, size_t ws_size,
                              hipStream_t stream) {
    const float* x = (const float*)d_in[0];
    const int* ei = (const int*)d_in[1];
    const int* batch = (const int*)d_in[2];
    const float* Wc = (const float*)d_in[3];
    const float* bc = (const float*)d_in[4];
    const float* gc = (const float*)d_in[5];
    const float* bec = (const float*)d_in[6];
    const float* Wh0 = (const float*)d_in[7];
    const float* bh0 = (const float*)d_in[8];
    const float* gh0 = (const float*)d_in[9];
    const float* beh0 = (const float*)d_in[10];
    const float* Wh1 = (const float*)d_in[11];
    const float* bh1 = (const float*)d_in[12];
    const float* gh1 = (const float*)d_in[13];
    const float* beh1 = (const float*)d_in[14];
    const float* Wout = (const float*)d_in[15];
    const float* bout = (const float*)d_in[16];
    float* out = (float*)d_out;

    const int* src = ei;
    const int* dst = ei + N_EDGES;

    char* base = (char*)d_ws;
    size_t woff = 0;
    auto alloc = [&](size_t bytes) -> char* {
        char* p = base + woff;
        woff = (woff + bytes + 255) & ~(size_t)255;
        return p;
    };
    _Float16* bufY = (_Float16*)alloc(sizeof(_Float16) * (size_t)N_NODES * D);
    _Float16* bufA = (_Float16*)alloc(sizeof(_Float16) * (size_t)N_NODES * D);
    float* dinv = (float*)alloc(sizeof(float) * N_NODES);
    int* csr = (int*)alloc(sizeof(int) * N_EDGES);
    // single zeroed region: cnt + cursor + part + stats
    char* zero_base = alloc(sizeof(int) * 2 * N_NODES + sizeof(float) * (32 * 256 + 512));
    int* cnt = (int*)zero_base;
    int* cursor = cnt + N_NODES;
    float* part = (float*)(cursor + N_NODES);
    float* stats = part + 32 * 256;
    float* sums = stats;
    float* sumsq = stats + 256;
    size_t zero_bytes = sizeof(int) * 2 * N_NODES + sizeof(float) * (32 * 256 + 512);
    int* offs = (int*)alloc(sizeof(int) * (N_NODES + 1));
    int* bsums = (int*)alloc(sizeof(int) * 512);
    float* avec = (float*)alloc(sizeof(float) * 256);
    float* cvec = (float*)alloc(sizeof(float) * 256);
    _Float16* WT = (_Float16*)alloc(sizeof(_Float16) * D * D);
    float* rvec = (float*)alloc(sizeof(float) * 128);
    int* starts = (int*)alloc(sizeof(int) * (N_GRAPHS + 1));
    float* pooled = (float*)alloc(sizeof(float) * N_GRAPHS * D);
    float* h0 = (float*)alloc(sizeof(float) * N_GRAPHS * DH);
    float* h1 = (float*)alloc(sizeof(float) * N_GRAPHS * DH);

    hipMemsetAsync(zero_base, 0, zero_bytes, stream);

    int nbl = (N_NODES + 255) / 256;
    int fill_grid = ((N_EDGES + FCHUNK - 1) / FCHUNK) * NPART;
    k_count_part<<<fill_grid, 256, 0, stream>>>(dst, cnt);
    k_scan1<<<nbl, 256, 0, stream>>>(cnt, offs, bsums, dinv, N_NODES);
    k_scan2<<<1, 512, 0, stream>>>(bsums, nbl);
    k_scan3<<<nbl, 256, 0, stream>>>(offs, bsums, N_NODES);
    k_fill_part<<<fill_grid, 256, 0, stream>>>(src, dst, offs, cursor, csr);

    int gemm_grid = (N_NODES + 63) / 64;
    for (int layer = 0; layer < 3; ++layer) {
        k_fold<<<65, 256, 0, stream>>>(Wc + layer * D * D, avec, cvec, layer > 0, WT, rvec);
        if (layer == 0)
            k_gemm<true><<<gemm_grid, 256, 0, stream>>>(x, WT, rvec, bufY, N_NODES);
        else
            k_gemm<false><<<gemm_grid, 256, 0, stream>>>(bufA, WT, rvec, bufY, N_NODES);
        k_aggregate<<<N_NODES / 16, 256, 0, stream>>>(
            (const h8*)bufY, offs, csr, dinv, bc + layer * D, (h8*)bufA, part);
        k_bn_coeffs<<<1, 128, 0, stream>>>(part, 32, 256, 128, gc + layer * D,
                                           bec + layer * D, avec, cvec, 1.0f / N_NODES);
    }

    k_starts<<<nbl, 256, 0, stream>>>(batch, starts);
    k_pool<<<N_GRAPHS, 256, 0, stream>>>((const h8*)bufA, starts, avec, cvec, pooled);

    k_dense<128><<<N_GRAPHS, 256, 0, stream>>>(pooled, Wh0, bh0, h0);
    k_head_stats<<<64, 256, 0, stream>>>(h0, sums, sumsq, N_GRAPHS);
    k_bn_coeffs<<<1, 256, 0, stream>>>(stats, 1, 512, 256, gh0, beh0, avec, cvec,
                                       1.0f / N_GRAPHS);
    k_head_apply<<<N_GRAPHS * DH / 4 / 256, 256, 0, stream>>>(h0, avec, cvec);

    k_dense<256><<<N_GRAPHS, 256, 0, stream>>>(h0, Wh1, bh1, h1);
    k_head_stats<<<64, 256, 0, stream>>>(h1, sums, sumsq, N_GRAPHS);
    k_bn_coeffs<<<1, 256, 0, stream>>>(stats, 1, 512, 256, gh1, beh1, avec, cvec,
                                       1.0f / N_GRAPHS);
    k_head_apply<<<N_GRAPHS * DH / 4 / 256, 256, 0, stream>>>(h1, avec, cvec);

    k_final<<<N_GRAPHS / 4, 256, 0, stream>>>(h1, Wout, bout, out);
}